// Round 10
// baseline (26257.361 us; speedup 1.0000x reference)
//
#include <hip/hip_runtime.h>
#include <math.h>

#define B 512
#define S_IN 128
#define S_OUT 64
#define T_DEC 63

// ---- ws layout (floats); total = 35,127,300 = proven round-2..9 floor ----
#define W_HT0 0
#define W_HT1 524288
#define W_CT1 1048576
#define W_BAR 1572864                   // 4 words: bar[0]=enc0 bar[1]=enc1 bar[2]=dec
#define W_HS0 1572868                   // hs0[t][feat(512)][m(512)] = 33,554,432
#define W_CT0 W_HS0                     // decoder-phase alias (hs0 dead)
#define W_PWT (W_HS0 + 524288)          // decoder-phase alias
#define WS_MIN (W_HS0 + 33554432)

// ===========================================================================
// Two-phase grid barrier (round-9, validated twice). Own counter per kernel.
// ===========================================================================
__device__ __forceinline__ void grid_bar2(unsigned* cnt, unsigned t)
{
    __syncthreads();
    if (threadIdx.x == 0) {
        __threadfence();
        __hip_atomic_fetch_add(cnt, 1u, __ATOMIC_RELAXED, __HIP_MEMORY_SCOPE_AGENT);
        const unsigned tgt1 = (2u*t + 1u) * 256u;
        while (__hip_atomic_load(cnt, __ATOMIC_RELAXED, __HIP_MEMORY_SCOPE_AGENT) < tgt1)
            __builtin_amdgcn_s_sleep(2);
        __threadfence();
        __hip_atomic_fetch_add(cnt, 1u, __ATOMIC_RELAXED, __HIP_MEMORY_SCOPE_AGENT);
        const unsigned tgt2 = (2u*t + 2u) * 256u;
        while (__hip_atomic_load(cnt, __ATOMIC_RELAXED, __HIP_MEMORY_SCOPE_AGENT) < tgt2)
            __builtin_amdgcn_s_sleep(2);
    }
    __syncthreads();
}

__device__ __forceinline__ void fma4(float* ac, float s, float4 v)
{
    ac[0] += s*v.x; ac[1] += s*v.y; ac[2] += s*v.z; ac[3] += s*v.w;
}

// ===========================================================================
// Persistent encoder layer L (0/1). 256 blocks x 1024 thr, 128 steps.
// Block: dir = b>>7, unit-pair up = (b&127)*2 -> 8 gate-cols (2 units).
// W slice gathered gate-interleaved to LDS once: [K][8], K=320 (l0) / 768 (l1).
// A staged per-16k double-buffered (r8 decoder pattern). State transposed
// hT/cT[unit][row]: l0 units = dir*256+u, l1 units = 512+dir*256+u -> exactly
// the decoder's (l0f,l0b,l1f,l1b) layout, no transpose prep needed.
// l0 also writes hs0[t][dir*256+u][m] (m-contiguous). 1 grid barrier/step.
// ===========================================================================
template<int L>
__global__ __launch_bounds__(1024)
void enc_persist(const float* __restrict__ Wih, const float* __restrict__ Whh,
                 const float* __restrict__ bias, const int* __restrict__ tok,
                 const float* __restrict__ emb, const float* __restrict__ hs0,
                 float* __restrict__ hs0_out, float* __restrict__ hT0,
                 float* __restrict__ hT1, float* __restrict__ cT,
                 unsigned* __restrict__ bar)
{
    constexpr int KE = (L==0) ? 64 : 512;     // emb / hs0 part
    constexpr int K  = KE + 256;
    constexpr int NK = K/16;
    constexpr int WSZ = K*8;                  // W floats in LDS

    extern __shared__ float smem[];
    float* Ws  = smem;                        // [K][8]
    float* As  = smem + WSZ;                  // 2 x [16][512]

    const int b = blockIdx.x, tid = threadIdx.x;
    const int dir = b >> 7;
    const int up  = (b & 127) * 2;

    const float* Wih_d = Wih + (size_t)dir*1024*KE;
    const float* Whh_d = Whh + (size_t)dir*1024*256;
    const float* b_d   = bias + dir*1024;

    // ---- one-time W gather into LDS ----
    {
        const int lc = tid >> 7;              // local col 0..7
        const int q  = tid & 127;
        const int n  = up*4 + lc;
        const int j  = (n & 3)*256 + (n >> 2);
        for (int k0 = q*4; k0 < K; k0 += 512) {
            float4 v;
            if (k0 < KE) v = *(const float4*)&Wih_d[(size_t)j*KE + k0];
            else         v = *(const float4*)&Whh_d[(size_t)j*256 + (k0-KE)];
            Ws[(k0+0)*8 + lc] = v.x;
            Ws[(k0+1)*8 + lc] = v.y;
            Ws[(k0+2)*8 + lc] = v.z;
            Ws[(k0+3)*8 + lc] = v.w;
        }
    }
    __syncthreads();

    const int m  = tid & 511;                 // GEMM row
    const int cg = tid >> 9;                  // 0/1 -> unit up+cg (wave-uniform)
    const int u  = up + cg;
    const float bi = b_d[u], bf = b_d[256+u], bg_ = b_d[512+u], bo = b_d[768+u];
    const int ub   = (L==0) ? dir*256 : 512 + dir*256;   // hT/cT unit base
    const int sj  = tid >> 6;                 // staging k-in-slice
    const int sr  = (tid & 63)*8;             // staging 8-row chunk
    const int esm = tid >> 1, esq = tid & 1;  // emb staging (L0)

    for (int t = 0; t < S_IN; ++t) {
        const float* hT_in  = (t & 1) ? hT1 : hT0;
        float*       hT_out = (t & 1) ? hT0 : hT1;
        const int t_eff = dir ? (S_IN-1-t) : t;

        int etok = 0;
        if (L==0) etok = tok[t_eff*B + esm];

        // prologue: stage regs for kt=0
        float4 pre0, pre1;
        if (L==0) {
            pre0 = *(const float4*)&emb[(size_t)etok*64 + esq*8];
            pre1 = *(const float4*)&emb[(size_t)etok*64 + esq*8 + 4];
        } else {
            const float* src = &hs0[((size_t)t_eff*512 + sj)*512 + sr];
            pre0 = *(const float4*)&src[0];
            pre1 = *(const float4*)&src[4];
        }
        float acc[4] = {};

        for (int kt = 0; kt < NK; ++kt) {
            float* buf = As + (kt & 1)*8192;
            if (L==0 && kt < 4) {
                const int j0 = esq*8;
                buf[(j0+0)*512+esm]=pre0.x; buf[(j0+1)*512+esm]=pre0.y;
                buf[(j0+2)*512+esm]=pre0.z; buf[(j0+3)*512+esm]=pre0.w;
                buf[(j0+4)*512+esm]=pre1.x; buf[(j0+5)*512+esm]=pre1.y;
                buf[(j0+6)*512+esm]=pre1.z; buf[(j0+7)*512+esm]=pre1.w;
            } else {
                *(float4*)&buf[sj*512 + sr]     = pre0;
                *(float4*)&buf[sj*512 + sr + 4] = pre1;
            }
            if (kt+1 < NK) {
                const int kb = (kt+1)*16;
                if (L==0 && kt+1 < 4) {
                    pre0 = *(const float4*)&emb[(size_t)etok*64 + kb + esq*8];
                    pre1 = *(const float4*)&emb[(size_t)etok*64 + kb + esq*8 + 4];
                } else if (L==1 && kt+1 < 32) {
                    const float* src = &hs0[((size_t)t_eff*512 + kb + sj)*512 + sr];
                    pre0 = *(const float4*)&src[0];
                    pre1 = *(const float4*)&src[4];
                } else {
                    const float* src = &hT_in[(size_t)(ub + kb - KE + sj)*512 + sr];
                    pre0 = *(const float4*)&src[0];
                    pre1 = *(const float4*)&src[4];
                }
            }
            __syncthreads();
            const int kg = kt*16;
            #pragma unroll
            for (int kk=0;kk<16;kk++){
                const float4 w = *(const float4*)&Ws[(kg+kk)*8 + cg*4];
                const float a  = buf[kk*512 + m];
                fma4(acc, a, w);
            }
        }

        // ---- LSTM epilogue (1 unit per thread; i,f,g,o = acc[0..3]) ----
        {
            float xi=acc[0]+bi, xf=acc[1]+bf, xg=acc[2]+bg_, xo=acc[3]+bo;
            float ig=1.f/(1.f+expf(-xi)), fg=1.f/(1.f+expf(-xf));
            float gg=tanhf(xg), og=1.f/(1.f+expf(-xo));
            const size_t ci = (size_t)(ub + u)*512 + m;
            const float cn = fg*cT[ci] + ig*gg;     // in-place (owner thread)
            const float hn = og*tanhf(cn);
            cT[ci] = cn; hT_out[ci] = hn;
            if (L==0)
                hs0_out[((size_t)t_eff*512 + dir*256 + u)*512 + m] = hn;
        }

        grid_bar2(bar, (unsigned)t);
    }
}

// ===========================================================================
// Prep: pW -> pwt[k][v] (decoder proj weight transpose).
// ===========================================================================
__global__ void prep_kernel(const float* __restrict__ pW, float* __restrict__ pwt)
{
    const int i = blockIdx.x*blockDim.x + threadIdx.x;
    if (i < 131072) {
        const int k = i >> 7, v = i & 127;
        pwt[i] = pW[(size_t)v*1024 + k];
    }
}

// ===========================================================================
// Persistent decoder (round-8/9 validated, verbatim).
// ===========================================================================
__global__ __launch_bounds__(1024)
void dec_persist(const float* __restrict__ Wih, const float* __restrict__ Whh,
                 const float* __restrict__ bias, const int* __restrict__ tok,
                 const float* __restrict__ emb, const float* __restrict__ pwt,
                 const float* __restrict__ pb, float* __restrict__ hT0,
                 float* __restrict__ hT1, float* __restrict__ cT0,
                 float* __restrict__ cT1, unsigned* __restrict__ bar,
                 float* __restrict__ dout)
{
    extern __shared__ float smem[];
    float* Ws = smem;                    // [1088][16]          69632 B
    float* As = smem + 17408;            // 2 x [16][512]       65536 B
    float* cs0  = As;                    // proj scratch aliases (seq. safe)
    float* cs1  = As + 1024;
    float* part = As + 2048;
    float* ls   = As + 4096;

    const int b = blockIdx.x, tid = threadIdx.x;
    const int bn0 = b*16;

    // ---- one-time W preload into LDS (gate-interleaved gather) ----
    {
        const int col = tid >> 6;
        const int n_g = bn0 + col;
        const int wrow = (n_g & 3)*1024 + (n_g >> 2);
        for (int k0 = (tid & 63)*4; k0 < 1088; k0 += 256) {
            float4 v;
            if (k0 < 64) v = *(const float4*)&Wih[(size_t)wrow*64 + k0];
            else         v = *(const float4*)&Whh[(size_t)wrow*1024 + (k0-64)];
            Ws[(k0+0)*16 + col] = v.x;
            Ws[(k0+1)*16 + col] = v.y;
            Ws[(k0+2)*16 + col] = v.z;
            Ws[(k0+3)*16 + col] = v.w;
        }
    }
    __syncthreads();

    const int m   = tid & 511;
    const int tn  = (tid >> 9) << 3;
    const int jh  = (bn0 + tn) >> 2;
    const float bi0 = bias[jh],   bf0 = bias[1024+jh],   bg0 = bias[2048+jh],   bo0 = bias[3072+jh];
    const float bi1 = bias[jh+1], bf1 = bias[1024+jh+1], bg1 = bias[2048+jh+1], bo1 = bias[3072+jh+1];
    const int sj  = tid >> 6;
    const int sr  = (tid & 63)*8;
    const int esm = tid >> 1, esq = tid & 1;

    for (int t = 0; t < T_DEC; ++t) {
        const float* hT_in  = (t & 1) ? hT1 : hT0;
        float*       hT_out = (t & 1) ? hT0 : hT1;
        const float* cT_in  = (t & 1) ? cT0 : cT1;
        float*       cT_out = (t & 1) ? cT1 : cT0;

        const int etok = tok[esm*S_OUT + t];

        float4 pre0 = *(const float4*)&emb[(size_t)etok*64 + esq*8];
        float4 pre1 = *(const float4*)&emb[(size_t)etok*64 + esq*8 + 4];
        float acc[8] = {};

        for (int kt = 0; kt < 68; ++kt) {
            float* buf = As + (kt & 1)*8192;
            if (kt < 4) {
                const int j0 = esq*8;
                buf[(j0+0)*512+esm]=pre0.x; buf[(j0+1)*512+esm]=pre0.y;
                buf[(j0+2)*512+esm]=pre0.z; buf[(j0+3)*512+esm]=pre0.w;
                buf[(j0+4)*512+esm]=pre1.x; buf[(j0+5)*512+esm]=pre1.y;
                buf[(j0+6)*512+esm]=pre1.z; buf[(j0+7)*512+esm]=pre1.w;
            } else {
                *(float4*)&buf[sj*512 + sr]     = pre0;
                *(float4*)&buf[sj*512 + sr + 4] = pre1;
            }
            if (kt+1 < 68) {
                if (kt+1 < 4) {
                    pre0 = *(const float4*)&emb[(size_t)etok*64 + (kt+1)*16 + esq*8];
                    pre1 = *(const float4*)&emb[(size_t)etok*64 + (kt+1)*16 + esq*8 + 4];
                } else {
                    const float* src = &hT_in[(size_t)((kt+1)*16 - 64 + sj)*512 + sr];
                    pre0 = *(const float4*)&src[0];
                    pre1 = *(const float4*)&src[4];
                }
            }
            __syncthreads();
            const int kg = kt*16;
            #pragma unroll
            for (int kk=0;kk<16;kk++){
                const float4 w0 = *(const float4*)&Ws[(kg+kk)*16 + tn];
                const float4 w1 = *(const float4*)&Ws[(kg+kk)*16 + tn + 4];
                const float a  = buf[kk*512 + m];
                fma4(acc+0, a, w0);
                fma4(acc+4, a, w1);
            }
        }

        {
            float xi=acc[0]+bi0, xf=acc[1]+bf0, xg=acc[2]+bg0, xo=acc[3]+bo0;
            float ig=1.f/(1.f+expf(-xi)), fg=1.f/(1.f+expf(-xf));
            float gg=tanhf(xg), og=1.f/(1.f+expf(-xo));
            const size_t ci = (size_t)jh*512 + m;
            const float cn = fg*cT_in[ci] + ig*gg, hn = og*tanhf(cn);
            cT_out[ci] = cn; hT_out[ci] = hn;
        }
        {
            float xi=acc[4]+bi1, xf=acc[5]+bf1, xg=acc[6]+bg1, xo=acc[7]+bo1;
            float ig=1.f/(1.f+expf(-xi)), fg=1.f/(1.f+expf(-xf));
            float gg=tanhf(xg), og=1.f/(1.f+expf(-xo));
            const size_t ci = (size_t)(jh+1)*512 + m;
            const float cn = fg*cT_in[ci] + ig*gg, hn = og*tanhf(cn);
            cT_out[ci] = cn; hT_out[ci] = hn;
        }

        grid_bar2(bar, (unsigned)t);

        {
            const float2 v = *(const float2*)&cT_out[(size_t)tid*512 + 2*b];
            cs0[tid] = v.x; cs1[tid] = v.y;
        }
        __syncthreads();
        {
            const int kgp = tid >> 7, pc = tid & 127;
            float a0 = 0.f, a1 = 0.f;
            const int k0 = kgp*128;
            #pragma unroll 4
            for (int ki=0; ki<128; ++ki){
                const float w = pwt[(size_t)(k0+ki)*128 + pc];
                a0 += w*cs0[k0+ki];
                a1 += w*cs1[k0+ki];
            }
            part[(kgp*2+0)*128 + pc] = a0;
            part[(kgp*2+1)*128 + pc] = a1;
        }
        __syncthreads();
        if (tid < 256) {
            const int pr = tid >> 7, pc = tid & 127;
            float s = pb[pc];
            #pragma unroll
            for (int kg2=0; kg2<8; ++kg2) s += part[(kg2*2+pr)*128 + pc];
            ls[pr*128 + pc] = s;
        }
        __syncthreads();
        if (tid < 128) {
            const int r = tid >> 6, lane = tid & 63;
            const int gb = 2*b + r;
            const float v0 = ls[r*128 + lane], v1 = ls[r*128 + lane + 64];
            float mv; int mi;
            if (v1 > v0){ mv=v1; mi=lane+64; } else { mv=v0; mi=lane; }
            #pragma unroll
            for (int o=32;o>=1;o>>=1){
                const float ov = __shfl_xor(mv, o);
                const int   oi = __shfl_xor(mi, o);
                if (ov > mv || (ov == mv && oi < mi)){ mv=ov; mi=oi; }
            }
            float e = expf(v0-mv) + expf(v1-mv);
            #pragma unroll
            for (int o=32;o>=1;o>>=1) e += __shfl_xor(e, o);
            if (lane == 0){
                const int tnx = tok[gb*S_OUT + t + 1];
                const float logp = ls[r*128 + tnx] - mv - logf(e);
                const float cn = ((t==0)?0.f:dout[T_DEC*B + gb]) + logp;
                dout[T_DEC*B + gb] = cn;
                dout[t*B + gb] = (float)mi;
            }
        }
        __syncthreads();
    }
}

__global__ void zero_kernel(float* __restrict__ p, int n4){
    int i = blockIdx.x*blockDim.x + threadIdx.x;
    if (i < n4) *(float4*)&p[i*4] = float4{0.f,0.f,0.f,0.f};
}

extern "C" void kernel_launch(void* const* d_in, const int* in_sizes, int n_in,
                              void* d_out, int out_size, void* d_ws, size_t ws_size,
                              hipStream_t stream)
{
    const int*   input_tokens  = (const int*)d_in[0];
    const int*   output_tokens = (const int*)d_in[1];
    const float* in_emb  = (const float*)d_in[2];
    const float* eWih0   = (const float*)d_in[3];
    const float* eWhh0   = (const float*)d_in[4];
    const float* eb0     = (const float*)d_in[5];
    const float* eWih1   = (const float*)d_in[6];
    const float* eWhh1   = (const float*)d_in[7];
    const float* eb1     = (const float*)d_in[8];
    const float* out_emb = (const float*)d_in[9];
    const float* dWih    = (const float*)d_in[10];
    const float* dWhh    = (const float*)d_in[11];
    const float* db      = (const float*)d_in[12];
    const float* pW      = (const float*)d_in[13];
    const float* pb      = (const float*)d_in[14];

    if (ws_size < (size_t)WS_MIN * 4) return;

    float* ws   = (float*)d_ws;
    float* dout = (float*)d_out;

    float* hT0    = ws + W_HT0;
    float* hT1    = ws + W_HT1;
    float* cT1    = ws + W_CT1;
    unsigned* bar = (unsigned*)(ws + W_BAR);
    float* hs0    = ws + W_HS0;
    float* cT0    = ws + W_CT0;    // decoder alias (hs0 dead)
    float* pwt    = ws + W_PWT;    // decoder alias

    // zero hT0, hT1, cT1, bar  (= first 1,572,868 floats; /4 exact)
    zero_kernel<<<(W_HS0/4 + 255)/256, 256, 0, stream>>>(ws, W_HS0/4);

    // ---- persistent encoder layer 0 (writes hs0 + hT/cT units 0..511) ----
    enc_persist<0><<<256, 1024, (320*8 + 2*8192)*4, stream>>>(
        eWih0, eWhh0, eb0, input_tokens, in_emb, nullptr, hs0,
        hT0, hT1, cT1, bar + 0);

    // ---- persistent encoder layer 1 (reads hs0; hT/cT units 512..1023) ----
    enc_persist<1><<<256, 1024, (768*8 + 2*8192)*4, stream>>>(
        eWih1, eWhh1, eb1, nullptr, nullptr, hs0, nullptr,
        hT0, hT1, cT1, bar + 1);

    // ---- prep: proj weight transpose (hs0 dead from here) ----
    prep_kernel<<<512, 256, 0, stream>>>(pW, pwt);

    // ---- persistent decoder (round-8/9 validated) ----
    dec_persist<<<256, 1024, 135168, stream>>>(dWih, dWhh, db, output_tokens,
                                               out_emb, pwt, pb, hT0, hT1,
                                               cT0, cT1, bar + 2, dout);
}